// Round 1
// baseline (164.467 us; speedup 1.0000x reference)
//
#include <hip/hip_runtime.h>
#include <cstdint>
#include <cstddef>

typedef __attribute__((ext_vector_type(8))) short short8;
typedef __attribute__((ext_vector_type(4))) float floatx4;
typedef __attribute__((ext_vector_type(16))) float floatx16;
typedef __attribute__((ext_vector_type(4))) short short4v;
typedef unsigned short u16;
typedef unsigned int u32;

#define B_   2
#define T_   2048
#define D_   1024
#define H_   16
#define HKV_ 4
#define HD_  64
#define KV_  256
#define M_   4096   // B*T
#define QS_  1536   // fused QKV row stride

#define NX   4194304
#define NWQ  1048576
#define NWK  262144
#define NWV  262144
#define NWP  1048576
#define NCAST (NX + NWQ + NWK + NWV + NWP)
#define CAST_BLOCKS (NCAST / 1024)
#define TAB_BLOCKS  256

__device__ __forceinline__ float b2f(u16 u) {
    union { u32 i; float f; } v; v.i = ((u32)u) << 16; return v.f;
}
__device__ __forceinline__ u16 f2b(float f) {
    union { float f; u32 i; } v; v.f = f;
    u32 r = v.i + 0x7FFF + ((v.i >> 16) & 1);
    return (u16)(r >> 16);
}
__device__ __forceinline__ u32 pack_hi(float a, float b) {
    union { float f; u32 u; } ua, ub; ua.f = a; ub.f = b;
    return (ua.u >> 16) | (ub.u & 0xFFFF0000u);
}

__device__ __forceinline__ void async16(const u16* g, u16* l) {
    __builtin_amdgcn_global_load_lds(
        (const __attribute__((address_space(1))) u32*)g,
        (__attribute__((address_space(3))) u32*)l, 16, 0, 0);
}

// v_cvt_pk_bf16_f32: dst.lo16 = bf16(lo), dst.hi16 = bf16(hi)  (RNE)
__device__ __forceinline__ u32 cvtpk(float lo, float hi) {
    u32 r;
    asm("v_cvt_pk_bf16_f32 %0, %1, %2" : "=v"(r) : "v"(lo), "v"(hi));
    return r;
}
// v_permlane32_swap_b32: a.hi-lanes <-> b.lo-lanes
__device__ __forceinline__ void swap32(u32& a, u32& b) {
    asm volatile("v_permlane32_swap_b32 %0, %1" : "+v"(a), "+v"(b));
}
__device__ __forceinline__ void swap32f(float& a, float& b) {
    asm volatile("v_permlane32_swap_b32 %0, %1" : "+v"(a), "+v"(b));
}
__device__ __forceinline__ short8 pkfrag(u32 w0, u32 w1, u32 w2, u32 w3) {
    union { u32 w[4]; short8 s; } u;
    u.w[0] = w0; u.w[1] = w1; u.w[2] = w2; u.w[3] = w3;
    return u.s;
}

// ---------------------------------------------------------------------------
// prep: all fp32->bf16 casts + RoPE cos/sin table.
// ---------------------------------------------------------------------------
__global__ __launch_bounds__(256) void prep(const float* __restrict__ x,
                                            const float* __restrict__ wq,
                                            const float* __restrict__ wk,
                                            const float* __restrict__ wv,
                                            const float* __restrict__ wp,
                                            u16* __restrict__ dst,
                                            float2* __restrict__ tab) {
    int blk = blockIdx.x;
    if (blk < CAST_BLOCKS) {
        int i = blk * 1024 + threadIdx.x * 4;
        const float* src; int off;
        if      (i < NX)                  { src = x;  off = i; }
        else if (i < NX+NWQ)              { src = wq; off = i - NX; }
        else if (i < NX+NWQ+NWK)          { src = wk; off = i - (NX+NWQ); }
        else if (i < NX+NWQ+NWK+NWV)      { src = wv; off = i - (NX+NWQ+NWK); }
        else                              { src = wp; off = i - (NX+NWQ+NWK+NWV); }
        float4 v = *(const float4*)(src + off);
        short4v o;
        o.x = (short)f2b(v.x); o.y = (short)f2b(v.y);
        o.z = (short)f2b(v.z); o.w = (short)f2b(v.w);
        *(short4v*)(dst + i) = o;
    } else {
        int idx = (blk - CAST_BLOCKS) * 256 + threadIdx.x;
        int t = idx >> 5, i = idx & 31;
        float freq = exp2f(-(float)i * (13.287712379549449f / 32.0f));
        float ang = (float)t * freq;
        tab[idx] = make_float2(cosf(ang), sinf(ang));
    }
}

// ---------------------------------------------------------------------------
// QKV GEMM: 128x64 tile, BK=64 as TWO BK=32 half-tiles per barrier.
// Fused epilogue: RMSNorm+RoPE+gain for Q/K cols, V transposed to Vt.
// ---------------------------------------------------------------------------
__global__ __launch_bounds__(256, 3) void gemm_qkv(const u16* __restrict__ A,
                                                   const u16* __restrict__ W,
                                                   u16* __restrict__ C,
                                                   u16* __restrict__ Vt,
                                                   const float* __restrict__ gain,
                                                   const float2* __restrict__ tab) {
    const int K = D_;
    __shared__ u16 As[2][2][128 * 32];
    __shared__ u16 Bs[2][2][64 * 32];
    const int t = threadIdx.x;
    const int wave = t >> 6, lane = t & 63;
    const int quad = lane >> 4, l16 = lane & 15;
    const int wm = wave * 32;
    const int m0 = blockIdx.y * 128, n0 = blockIdx.x * 64;

    floatx4 acc[2][4];
#pragma unroll
    for (int i = 0; i < 2; i++)
#pragma unroll
        for (int j = 0; j < 4; j++) acc[i][j] = (floatx4){0.f, 0.f, 0.f, 0.f};

    const int sr = t >> 2, sc = (t & 3) * 8;
    const u16* ga = A + (size_t)(m0 + sr) * K + sc;
    const u16* gb = W + (size_t)(n0 + sr) * K + sc;

    auto stage = [&](int buf, int half, int koff) {
        async16(ga + koff, As[buf][half] + t * 8);
        async16(ga + koff + (size_t)64 * K, As[buf][half] + t * 8 + 64 * 32);
        async16(gb + koff, Bs[buf][half] + t * 8);
    };

    stage(0, 0, 0);
    stage(0, 1, 32);

    int cur = 0;
    for (int kt = 0; kt < K; kt += 64) {
        __syncthreads();
        if (kt + 64 < K) {
            stage(cur ^ 1, 0, kt + 64);
            stage(cur ^ 1, 1, kt + 96);
        }
#pragma unroll
        for (int half = 0; half < 2; half++) {
            short8 af[2], bf[4];
#pragma unroll
            for (int mt = 0; mt < 2; mt++)
                af[mt] = *(const short8*)(As[cur][half] + (wm + mt * 16 + l16) * 32 + quad * 8);
#pragma unroll
            for (int nt = 0; nt < 4; nt++)
                bf[nt] = *(const short8*)(Bs[cur][half] + (nt * 16 + l16) * 32 + quad * 8);
#pragma unroll
            for (int mt = 0; mt < 2; mt++)
#pragma unroll
                for (int nt = 0; nt < 4; nt++)
                    acc[mt][nt] = __builtin_amdgcn_mfma_f32_16x16x32_bf16(
                        af[mt], bf[nt], acc[mt][nt], 0, 0, 0);
        }
        cur ^= 1;
    }

    const int col0 = n0;               // 64-aligned: exactly one head-block
    if (col0 < 1280) {
        float gs = (col0 < 1024)
                 ? gain[col0 >> 6] * (0.125f * 1.4426950408889634f)
                 : 1.0f;
#pragma unroll
        for (int mt = 0; mt < 2; mt++)
#pragma unroll
            for (int r = 0; r < 4; r++) {
                int row = m0 + wm + mt * 16 + quad * 4 + r;
                int tt = row & (T_ - 1);
                float v0 = acc[mt][0][r], v1 = acc[mt][1][r];
                float v2 = acc[mt][2][r], v3 = acc[mt][3][r];
                float ss = v0 * v0 + v1 * v1 + v2 * v2 + v3 * v3;
                ss += __shfl_xor(ss, 1); ss += __shfl_xor(ss, 2);
                ss += __shfl_xor(ss, 4); ss += __shfl_xor(ss, 8);
                float inv = rsqrtf(ss * (1.0f / 64.0f) + 1.1920929e-7f);
                v0 *= inv; v1 *= inv; v2 *= inv; v3 *= inv;
                float2 cs0 = tab[tt * 32 + l16];
                float2 cs1 = tab[tt * 32 + 16 + l16];
                float o0 = (v0 * cs0.x + v2 * cs0.y) * gs;
                float o1 = (v1 * cs1.x + v3 * cs1.y) * gs;
                float o2 = (v2 * cs0.x - v0 * cs0.y) * gs;
                float o3 = (v3 * cs1.x - v1 * cs1.y) * gs;
                u16* cp = C + (size_t)row * QS_ + col0 + l16;
                cp[0]  = f2b(o0);
                cp[16] = f2b(o1);
                cp[32] = f2b(o2);
                cp[48] = f2b(o3);
            }
    } else {
        const int g = (col0 - 1280) >> 6;
#pragma unroll
        for (int mt = 0; mt < 2; mt++)
#pragma unroll
            for (int r = 0; r < 4; r++) {
                int row = m0 + wm + mt * 16 + quad * 4 + r;
                int tt = row & (T_ - 1);
                int bb = row >> 11;
#pragma unroll
                for (int nt = 0; nt < 4; nt++)
                    Vt[(size_t)((bb * 4 + g) * 64 + nt * 16 + l16) * T_ + tt] =
                        f2b(acc[mt][nt][r]);
            }
    }
}

// ---------------------------------------------------------------------------
// Output-projection GEMM: 128x64 tile, BK=64 (two halves), plain fp32 stores.
// ---------------------------------------------------------------------------
__global__ __launch_bounds__(256, 3) void gemm_proj(const u16* __restrict__ A,
                                                    const u16* __restrict__ W,
                                                    float* __restrict__ C) {
    const int K = D_;
    __shared__ u16 As[2][2][128 * 32];
    __shared__ u16 Bs[2][2][64 * 32];
    const int t = threadIdx.x;
    const int wave = t >> 6, lane = t & 63;
    const int quad = lane >> 4, l16 = lane & 15;
    const int wm = wave * 32;
    const int m0 = blockIdx.y * 128, n0 = blockIdx.x * 64;

    floatx4 acc[2][4];
#pragma unroll
    for (int i = 0; i < 2; i++)
#pragma unroll
        for (int j = 0; j < 4; j++) acc[i][j] = (floatx4){0.f, 0.f, 0.f, 0.f};

    const int sr = t >> 2, sc = (t & 3) * 8;
    const u16* ga = A + (size_t)(m0 + sr) * K + sc;
    const u16* gb = W + (size_t)(n0 + sr) * K + sc;

    auto stage = [&](int buf, int half, int koff) {
        async16(ga + koff, As[buf][half] + t * 8);
        async16(ga + koff + (size_t)64 * K, As[buf][half] + t * 8 + 64 * 32);
        async16(gb + koff, Bs[buf][half] + t * 8);
    };

    stage(0, 0, 0);
    stage(0, 1, 32);

    int cur = 0;
    for (int kt = 0; kt < K; kt += 64) {
        __syncthreads();
        if (kt + 64 < K) {
            stage(cur ^ 1, 0, kt + 64);
            stage(cur ^ 1, 1, kt + 96);
        }
#pragma unroll
        for (int half = 0; half < 2; half++) {
            short8 af[2], bf[4];
#pragma unroll
            for (int mt = 0; mt < 2; mt++)
                af[mt] = *(const short8*)(As[cur][half] + (wm + mt * 16 + l16) * 32 + quad * 8);
#pragma unroll
            for (int nt = 0; nt < 4; nt++)
                bf[nt] = *(const short8*)(Bs[cur][half] + (nt * 16 + l16) * 32 + quad * 8);
#pragma unroll
            for (int mt = 0; mt < 2; mt++)
#pragma unroll
                for (int nt = 0; nt < 4; nt++)
                    acc[mt][nt] = __builtin_amdgcn_mfma_f32_16x16x32_bf16(
                        af[mt], bf[nt], acc[mt][nt], 0, 0, 0);
        }
        cur ^= 1;
    }

#pragma unroll
    for (int mt = 0; mt < 2; mt++)
#pragma unroll
        for (int nt = 0; nt < 4; nt++)
#pragma unroll
            for (int r = 0; r < 4; r++) {
                int row = m0 + wm + mt * 16 + quad * 4 + r;
                int col = n0 + nt * 16 + l16;
                C[(size_t)row * D_ + col] = acc[mt][nt][r];
            }
}

// ---------------------------------------------------------------------------
// Flash attention (causal), 32x32x16 MFMA, in-register softmax (cvt_pk +
// permlane32_swap), triple-buffered K/V with counted vmcnt(4) + raw s_barrier
// (one barrier/tile, 2-tile prefetch depth). Block = 4 waves x 32 q-rows =
// 128 q-rows. Causal balance: block u does q-tile u keys [0,u+1) -> buf0 and
// q-tile 15-u keys [16-u,32-2u) -> buf1; every block exactly 17 iterations.
// Grid (16,16,2)=512 blocks = 2/CU; LDS 80KB (48KB K/V 3-buf + 32KB Ot).
// ---------------------------------------------------------------------------
__global__ __launch_bounds__(256, 2) void flash(const u16* __restrict__ QKV,
                                                const u16* __restrict__ Vtr,
                                                float* __restrict__ Opart,
                                                float* __restrict__ Lpart) {
    const int u  = blockIdx.x;
    const int h  = blockIdx.y;
    const int b  = blockIdx.z;
    const int g  = h >> 2;
    const int w    = threadIdx.x >> 6;
    const int lane = threadIdx.x & 63;
    const int ln31 = lane & 31;
    const int hi   = lane >> 5;
    const int swz  = lane & 7;

    __shared__ u16 Kb[3][4096];
    __shared__ u16 Vb[3][4096];
    __shared__ float Ot[4][2048];

    const int srow = w * 16 + (lane >> 3);
    const int sseg = (lane & 7) ^ ((lane >> 3) & 7);
    const u16* kgb = QKV + (size_t)(b * T_ + srow) * QS_ + D_ + g * 64 + sseg * 8;
    const u16* vgb = Vtr + (size_t)((b * 4 + g) * 64 + srow) * T_ + sseg * 8;

    auto stage = [&](int tile, int bi) {
        const u16* kg = kgb + (size_t)tile * 64 * QS_;
        const u16* vg = vgb + (size_t)tile * 64;
        u16* kl = &Kb[bi][w * 1024 + lane * 8];
        u16* vl = &Vb[bi][w * 1024 + lane * 8];
        async16(kg, kl);
        async16(kg + (size_t)8 * QS_, kl + 512);
        async16(vg, vl);
        async16(vg + (size_t)8 * T_, vl + 512);
    };
    auto tileOf = [&](int gidx) { return (gidx <= u) ? gidx : gidx + 15 - 2 * u; };

    stage(tileOf(0), 0);
    stage(tileOf(1), 1);

    int gi = 0;
    for (int seg = 0; seg < 2; ++seg) {
        const int jt   = seg ? 15 - u : u;
        const int nIt  = seg ? 16 - u : u + 1;
        const int qrow = jt * 128 + w * 32 + ln31;

        const u16* qp = QKV + (size_t)(b * T_ + qrow) * QS_ + h * HD_;
        short8 aq[4];
#pragma unroll
        for (int kc = 0; kc < 4; kc++)
            aq[kc] = *(const short8*)(qp + kc * 16 + hi * 8);

        floatx16 acc[2];
#pragma unroll
        for (int dh = 0; dh < 2; dh++)
#pragma unroll
            for (int i = 0; i < 16; i++) acc[dh][i] = 0.f;
        float l = 0.f;

        for (int itn = 0; itn < nIt; ++itn, ++gi) {
            const int tk = tileOf(gi);
            // counted vmcnt: own tile-gi loads done; tile gi+1 stays in flight
            if (gi == 16) asm volatile("s_waitcnt vmcnt(0)" ::: "memory");
            else          asm volatile("s_waitcnt vmcnt(4)" ::: "memory");
            __builtin_amdgcn_s_barrier();
            asm volatile("" ::: "memory");

            const int bc = gi % 3;
            if (gi + 2 <= 16) stage(tileOf(gi + 2), (gi + 2) % 3);

            const u16* Kp = &Kb[bc][0];
            const u16* Vp = &Vb[bc][0];
            short8 kf[2][4], vfr[2][4];
#pragma unroll
            for (int kh = 0; kh < 2; kh++)
#pragma unroll
                for (int kc = 0; kc < 4; kc++)
                    kf[kh][kc] = *(const short8*)(Kp + (kh * 32 + ln31) * 64 +
                                                  (((kc * 2 + hi) ^ swz) << 3));
#pragma unroll
            for (int dh = 0; dh < 2; dh++)
#pragma unroll
                for (int kc = 0; kc < 4; kc++)
                    vfr[dh][kc] = *(const short8*)(Vp + (dh * 32 + ln31) * 64 +
                                                   (((kc * 2 + hi) ^ swz) << 3));

            floatx16 s[2];
#pragma unroll
            for (int kh = 0; kh < 2; kh++)
#pragma unroll
                for (int i = 0; i < 16; i++) s[kh][i] = 0.f;

            __builtin_amdgcn_s_setprio(1);
#pragma unroll
            for (int kc = 0; kc < 4; kc++) {
                s[0] = __builtin_amdgcn_mfma_f32_32x32x16_bf16(kf[0][kc], aq[kc], s[0], 0, 0, 0);
                s[1] = __builtin_amdgcn_mfma_f32_32x32x16_bf16(kf[1][kc], aq[kc], s[1], 0, 0, 0);
            }
            __builtin_amdgcn_s_setprio(0);

            float p[2][16];
            if (tk >= 2 * jt) {
#pragma unroll
                for (int kh = 0; kh < 2; kh++)
#pragma unroll
                    for (int r = 0; r < 16; r++) {
                        int key = tk * 64 + kh * 32 + (r & 3) + ((r >> 2) << 3) + (hi << 2);
                        float e = __builtin_amdgcn_exp2f(s[kh][r]);
                        e = (key <= qrow) ? e : 0.f;
                        l += e; p[kh][r] = e;
                    }
            } else {
#pragma unroll
                for (int kh = 0; kh < 2; kh++)
#pragma unroll
                    for (int r = 0; r < 16; r++) {
                        float e = __builtin_amdgcn_exp2f(s[kh][r]);
                        l += e; p[kh][r] = e;
                    }
            }

            // in-register P -> bf16 B-fragments (keys become k-dim, hi*8+e)
            short8 pb[4];
#pragma unroll
            for (int kh = 0; kh < 2; kh++) {
                u32 a0 = cvtpk(p[kh][0], p[kh][1]),  b0 = cvtpk(p[kh][4], p[kh][5]);
                u32 c0 = cvtpk(p[kh][2], p[kh][3]),  d0 = cvtpk(p[kh][6], p[kh][7]);
                swap32(a0, b0); swap32(c0, d0);
                pb[kh * 2] = pkfrag(a0, c0, b0, d0);
                u32 a1 = cvtpk(p[kh][8],  p[kh][9]),  b1 = cvtpk(p[kh][12], p[kh][13]);
                u32 c1 = cvtpk(p[kh][10], p[kh][11]), d1 = cvtpk(p[kh][14], p[kh][15]);
                swap32(a1, b1); swap32(c1, d1);
                pb[kh * 2 + 1] = pkfrag(a1, c1, b1, d1);
            }

            __builtin_amdgcn_s_setprio(1);
#pragma unroll
            for (int kc = 0; kc < 4; kc++) {
                acc[0] = __builtin_amdgcn_mfma_f32_32x32x16_bf16(vfr[0][kc], pb[kc], acc[0], 0, 0, 0);
                acc[1] = __builtin_amdgcn_mfma_f32_32x32x16_bf16(vfr[1][kc], pb[kc], acc[1], 0, 0, 0);
            }
            __builtin_amdgcn_s_setprio(0);
        }

        // ---- segment epilogue: finalize l, transpose O via per-wave LDS ----
        float la = l, lb = l;
        swap32f(la, lb);                 // la = l[lane&31], lb = l[32+(lane&31)]
        float lt = la + lb;

        float* ot = &Ot[w][0];           // [32 q][64 d] f32, 16B-seg XOR swizzle
#pragma unroll
        for (int dh = 0; dh < 2; dh++)
#pragma unroll
            for (int g4 = 0; g4 < 4; g4++) {
                int ss = (dh * 8 + g4 * 2 + hi) ^ (ln31 & 7);
                float4 v = make_float4(acc[dh][g4 * 4 + 0], acc[dh][g4 * 4 + 1],
                                       acc[dh][g4 * 4 + 2], acc[dh][g4 * 4 + 3]);
                *(float4*)(ot + ln31 * 64 + ss * 4) = v;
            }
        asm volatile("s_waitcnt lgkmcnt(0)" ::: "memory");

        const int hq = lane >> 4;
        const int s4 = lane & 15;
        float* obase = Opart + (size_t)seg * 4194304 +
                       ((size_t)(b * 2048 + jt * 128 + w * 32)) * 1024 + h * HD_;
#pragma unroll
        for (int it = 0; it < 8; it++) {
            int q2 = it * 4 + hq;
            int ss = s4 ^ (q2 & 7);
            float4 v = *(const float4*)(ot + q2 * 64 + ss * 4);
            *(float4*)(obase + (size_t)q2 * 1024 + s4 * 4) = v;
        }
        if (lane < 32)
            Lpart[((size_t)seg * 4096 + b * 2048 + jt * 128 + w * 32 + lane) * 16 + h] = lt;
    }
}

// ---------------------------------------------------------------------------
// combine: Y[all rows] = (O0+O1) / (l0+l1)
// ---------------------------------------------------------------------------
__global__ __launch_bounds__(256) void combine(const float* __restrict__ Opart,
                                               const float* __restrict__ Lpart,
                                               u16* __restrict__ Y) {
    int e = (blockIdx.x * 256 + threadIdx.x) * 4;   // < 4*1024*1024
    int row = e >> 10, col = e & 1023;              // row = b*2048 + r
    int li = row * 16 + (col >> 6);
    float l0 = Lpart[li];
    float l1 = Lpart[li + 4096 * 16];
    float inv = 1.0f / (l0 + l1);
    size_t oi = (size_t)row * 1024 + col;
    float4 o0 = *(const float4*)(Opart + oi);
    float4 o1 = *(const float4*)(Opart + oi + (size_t)4194304);
    short4v y;
    y.x = (short)f2b((o0.x + o1.x) * inv); y.y = (short)f2b((o0.y + o1.y) * inv);
    y.z = (short)f2b((o0.z + o1.z) * inv); y.w = (short)f2b((o0.w + o1.w) * inv);
    *(short4v*)(Y + (size_t)row * D_ + col) = y;
}

// ---------------------------------------------------------------------------
extern "C" void kernel_launch(void* const* d_in, const int* in_sizes, int n_in,
                              void* d_out, int out_size, void* d_ws, size_t ws_size,
                              hipStream_t stream) {
    const float* x    = (const float*)d_in[0];
    const float* Wq   = (const float*)d_in[1];
    const float* Wk   = (const float*)d_in[2];
    const float* Wv   = (const float*)d_in[3];
    const float* Wp   = (const float*)d_in[4];
    const float* gain = (const float*)d_in[5];
    float* out = (float*)d_out;

    u16* xb   = (u16*)d_ws;
    u16* Wcat = xb + (size_t)NX;
    u16* Wpb  = Wcat + (size_t)(NWQ + NWK + NWV);
    u16* QKV  = Wpb + (size_t)NWP;
    u16* Vt   = QKV + (size_t)M_ * QS_;
    u16* Y    = Vt + (size_t)M_ * KV_;
    float2* tab = (float2*)(Y + (size_t)M_ * D_);          // 65536 float2
    float* Opart = (float*)(tab + 65536);                  // 2buf*4096*1024 f32
    float* Lpart = Opart + (size_t)8 * 1024 * 1024;        // 2buf*4096*16 f32

    prep<<<CAST_BLOCKS + TAB_BLOCKS, 256, 0, stream>>>(x, Wq, Wk, Wv, Wp, xb, tab);

    gemm_qkv<<<dim3(QS_ / 64, M_ / 128), 256, 0, stream>>>(xb, Wcat, QKV, Vt,
                                                           gain, tab);

    flash<<<dim3(16, H_, B_), 256, 0, stream>>>(QKV, Vt, Opart, Lpart);

    combine<<<4096, 256, 0, stream>>>(Opart, Lpart, Y);

    gemm_proj<<<dim3(D_ / 64, M_ / 128), 256, 0, stream>>>(Y, Wpb, out);
}

// Round 2
// 160.364 us; speedup vs baseline: 1.0256x; 1.0256x over previous
//
#include <hip/hip_runtime.h>
#include <cstdint>
#include <cstddef>

typedef __attribute__((ext_vector_type(8))) short short8;
typedef __attribute__((ext_vector_type(4))) float floatx4;
typedef __attribute__((ext_vector_type(16))) float floatx16;
typedef __attribute__((ext_vector_type(4))) short short4v;
typedef unsigned short u16;
typedef unsigned int u32;

#define B_   2
#define T_   2048
#define D_   1024
#define H_   16
#define HKV_ 4
#define HD_  64
#define KV_  256
#define M_   4096   // B*T
#define QS_  1536   // fused QKV row stride

#define NX   4194304
#define NWQ  1048576
#define NWK  262144
#define NWV  262144
#define NWP  1048576
#define NCAST (NX + NWQ + NWK + NWV + NWP)
#define CAST_BLOCKS (NCAST / 1024)
#define TAB_BLOCKS  256

__device__ __forceinline__ float b2f(u16 u) {
    union { u32 i; float f; } v; v.i = ((u32)u) << 16; return v.f;
}
__device__ __forceinline__ u16 f2b(float f) {
    union { float f; u32 i; } v; v.f = f;
    u32 r = v.i + 0x7FFF + ((v.i >> 16) & 1);
    return (u16)(r >> 16);
}

__device__ __forceinline__ void async16(const u16* g, u16* l) {
    __builtin_amdgcn_global_load_lds(
        (const __attribute__((address_space(1))) u32*)g,
        (__attribute__((address_space(3))) u32*)l, 16, 0, 0);
}

// v_cvt_pk_bf16_f32: dst.lo16 = bf16(lo), dst.hi16 = bf16(hi)  (RNE)
__device__ __forceinline__ u32 cvtpk(float lo, float hi) {
    u32 r;
    asm("v_cvt_pk_bf16_f32 %0, %1, %2" : "=v"(r) : "v"(lo), "v"(hi));
    return r;
}
// v_permlane32_swap_b32: a.hi-lanes <-> b.lo-lanes
__device__ __forceinline__ void swap32(u32& a, u32& b) {
    asm volatile("v_permlane32_swap_b32 %0, %1" : "+v"(a), "+v"(b));
}
__device__ __forceinline__ void swap32f(float& a, float& b) {
    asm volatile("v_permlane32_swap_b32 %0, %1" : "+v"(a), "+v"(b));
}
__device__ __forceinline__ short8 pkfrag(u32 w0, u32 w1, u32 w2, u32 w3) {
    union { u32 w[4]; short8 s; } u;
    u.w[0] = w0; u.w[1] = w1; u.w[2] = w2; u.w[3] = w3;
    return u.s;
}

// ---------------------------------------------------------------------------
// prep: all fp32->bf16 casts + RoPE cos/sin table.
// ---------------------------------------------------------------------------
__global__ __launch_bounds__(256) void prep(const float* __restrict__ x,
                                            const float* __restrict__ wq,
                                            const float* __restrict__ wk,
                                            const float* __restrict__ wv,
                                            const float* __restrict__ wp,
                                            u16* __restrict__ dst,
                                            float2* __restrict__ tab) {
    int blk = blockIdx.x;
    if (blk < CAST_BLOCKS) {
        int i = blk * 1024 + threadIdx.x * 4;
        const float* src; int off;
        if      (i < NX)                  { src = x;  off = i; }
        else if (i < NX+NWQ)              { src = wq; off = i - NX; }
        else if (i < NX+NWQ+NWK)          { src = wk; off = i - (NX+NWQ); }
        else if (i < NX+NWQ+NWK+NWV)      { src = wv; off = i - (NX+NWQ+NWK); }
        else                              { src = wp; off = i - (NX+NWQ+NWK+NWV); }
        float4 v = *(const float4*)(src + off);
        short4v o;
        o.x = (short)f2b(v.x); o.y = (short)f2b(v.y);
        o.z = (short)f2b(v.z); o.w = (short)f2b(v.w);
        *(short4v*)(dst + i) = o;
    } else {
        int idx = (blk - CAST_BLOCKS) * 256 + threadIdx.x;
        int t = idx >> 5, i = idx & 31;
        float freq = exp2f(-(float)i * (13.287712379549449f / 32.0f));
        float ang = (float)t * freq;
        tab[idx] = make_float2(cosf(ang), sinf(ang));
    }
}

// ---------------------------------------------------------------------------
// QKV GEMM: 128x64 tile, BK=64 as TWO BK=32 half-tiles per barrier.
// LDS XOR swizzle (both-sides): element (row, seg) stored at seg^((row>>1)&3)
// via pre-swizzled global source col; read with the same XOR -> 2-way (free)
// instead of 8-way bank conflict on ds_read_b128.
// Fused epilogue: RMSNorm+RoPE+gain for Q/K cols, V transposed to Vt.
// ---------------------------------------------------------------------------
__global__ __launch_bounds__(256, 3) void gemm_qkv(const u16* __restrict__ A,
                                                   const u16* __restrict__ W,
                                                   u16* __restrict__ C,
                                                   u16* __restrict__ Vt,
                                                   const float* __restrict__ gain,
                                                   const float2* __restrict__ tab) {
    const int K = D_;
    __shared__ u16 As[2][2][128 * 32];
    __shared__ u16 Bs[2][2][64 * 32];
    const int t = threadIdx.x;
    const int wave = t >> 6, lane = t & 63;
    const int quad = lane >> 4, l16 = lane & 15;
    const int wm = wave * 32;
    const int m0 = blockIdx.y * 128, n0 = blockIdx.x * 64;

    floatx4 acc[2][4];
#pragma unroll
    for (int i = 0; i < 2; i++)
#pragma unroll
        for (int j = 0; j < 4; j++) acc[i][j] = (floatx4){0.f, 0.f, 0.f, 0.f};

    const int sr = t >> 2;
    const int sc = (((t & 3) ^ ((t >> 3) & 3)) * 8);   // pre-swizzled source col
    const u16* ga = A + (size_t)(m0 + sr) * K + sc;
    const u16* gb = W + (size_t)(n0 + sr) * K + sc;

    auto stage = [&](int buf, int half, int koff) {
        async16(ga + koff, As[buf][half] + t * 8);
        async16(ga + koff + (size_t)64 * K, As[buf][half] + t * 8 + 64 * 32);
        async16(gb + koff, Bs[buf][half] + t * 8);
    };

    stage(0, 0, 0);
    stage(0, 1, 32);

    int cur = 0;
    for (int kt = 0; kt < K; kt += 64) {
        __syncthreads();
        if (kt + 64 < K) {
            stage(cur ^ 1, 0, kt + 64);
            stage(cur ^ 1, 1, kt + 96);
        }
#pragma unroll
        for (int half = 0; half < 2; half++) {
            short8 af[2], bf[4];
#pragma unroll
            for (int mt = 0; mt < 2; mt++) {
                int row = wm + mt * 16 + l16;
                af[mt] = *(const short8*)(As[cur][half] + row * 32 +
                                          ((quad ^ ((row >> 1) & 3)) << 3));
            }
#pragma unroll
            for (int nt = 0; nt < 4; nt++) {
                int row = nt * 16 + l16;
                bf[nt] = *(const short8*)(Bs[cur][half] + row * 32 +
                                          ((quad ^ ((row >> 1) & 3)) << 3));
            }
#pragma unroll
            for (int mt = 0; mt < 2; mt++)
#pragma unroll
                for (int nt = 0; nt < 4; nt++)
                    acc[mt][nt] = __builtin_amdgcn_mfma_f32_16x16x32_bf16(
                        af[mt], bf[nt], acc[mt][nt], 0, 0, 0);
        }
        cur ^= 1;
    }

    const int col0 = n0;               // 64-aligned: exactly one head-block
    if (col0 < 1280) {
        float gs = (col0 < 1024)
                 ? gain[col0 >> 6] * (0.125f * 1.4426950408889634f)
                 : 1.0f;
#pragma unroll
        for (int mt = 0; mt < 2; mt++)
#pragma unroll
            for (int r = 0; r < 4; r++) {
                int row = m0 + wm + mt * 16 + quad * 4 + r;
                int tt = row & (T_ - 1);
                float v0 = acc[mt][0][r], v1 = acc[mt][1][r];
                float v2 = acc[mt][2][r], v3 = acc[mt][3][r];
                float ss = v0 * v0 + v1 * v1 + v2 * v2 + v3 * v3;
                ss += __shfl_xor(ss, 1); ss += __shfl_xor(ss, 2);
                ss += __shfl_xor(ss, 4); ss += __shfl_xor(ss, 8);
                float inv = rsqrtf(ss * (1.0f / 64.0f) + 1.1920929e-7f);
                v0 *= inv; v1 *= inv; v2 *= inv; v3 *= inv;
                float2 cs0 = tab[tt * 32 + l16];
                float2 cs1 = tab[tt * 32 + 16 + l16];
                float o0 = (v0 * cs0.x + v2 * cs0.y) * gs;
                float o1 = (v1 * cs1.x + v3 * cs1.y) * gs;
                float o2 = (v2 * cs0.x - v0 * cs0.y) * gs;
                float o3 = (v3 * cs1.x - v1 * cs1.y) * gs;
                u16* cp = C + (size_t)row * QS_ + col0 + l16;
                cp[0]  = f2b(o0);
                cp[16] = f2b(o1);
                cp[32] = f2b(o2);
                cp[48] = f2b(o3);
            }
    } else {
        const int g = (col0 - 1280) >> 6;
#pragma unroll
        for (int mt = 0; mt < 2; mt++)
#pragma unroll
            for (int r = 0; r < 4; r++) {
                int row = m0 + wm + mt * 16 + quad * 4 + r;
                int tt = row & (T_ - 1);
                int bb = row >> 11;
#pragma unroll
                for (int nt = 0; nt < 4; nt++)
                    Vt[(size_t)((bb * 4 + g) * 64 + nt * 16 + l16) * T_ + tt] =
                        f2b(acc[mt][nt][r]);
            }
    }
}

// ---------------------------------------------------------------------------
// Output-projection GEMM: 128x64 tile, BK=64 (two halves), swizzled LDS,
// plain fp32 stores.
// ---------------------------------------------------------------------------
__global__ __launch_bounds__(256, 3) void gemm_proj(const u16* __restrict__ A,
                                                    const u16* __restrict__ W,
                                                    float* __restrict__ C) {
    const int K = D_;
    __shared__ u16 As[2][2][128 * 32];
    __shared__ u16 Bs[2][2][64 * 32];
    const int t = threadIdx.x;
    const int wave = t >> 6, lane = t & 63;
    const int quad = lane >> 4, l16 = lane & 15;
    const int wm = wave * 32;
    const int m0 = blockIdx.y * 128, n0 = blockIdx.x * 64;

    floatx4 acc[2][4];
#pragma unroll
    for (int i = 0; i < 2; i++)
#pragma unroll
        for (int j = 0; j < 4; j++) acc[i][j] = (floatx4){0.f, 0.f, 0.f, 0.f};

    const int sr = t >> 2;
    const int sc = (((t & 3) ^ ((t >> 3) & 3)) * 8);
    const u16* ga = A + (size_t)(m0 + sr) * K + sc;
    const u16* gb = W + (size_t)(n0 + sr) * K + sc;

    auto stage = [&](int buf, int half, int koff) {
        async16(ga + koff, As[buf][half] + t * 8);
        async16(ga + koff + (size_t)64 * K, As[buf][half] + t * 8 + 64 * 32);
        async16(gb + koff, Bs[buf][half] + t * 8);
    };

    stage(0, 0, 0);
    stage(0, 1, 32);

    int cur = 0;
    for (int kt = 0; kt < K; kt += 64) {
        __syncthreads();
        if (kt + 64 < K) {
            stage(cur ^ 1, 0, kt + 64);
            stage(cur ^ 1, 1, kt + 96);
        }
#pragma unroll
        for (int half = 0; half < 2; half++) {
            short8 af[2], bf[4];
#pragma unroll
            for (int mt = 0; mt < 2; mt++) {
                int row = wm + mt * 16 + l16;
                af[mt] = *(const short8*)(As[cur][half] + row * 32 +
                                          ((quad ^ ((row >> 1) & 3)) << 3));
            }
#pragma unroll
            for (int nt = 0; nt < 4; nt++) {
                int row = nt * 16 + l16;
                bf[nt] = *(const short8*)(Bs[cur][half] + row * 32 +
                                          ((quad ^ ((row >> 1) & 3)) << 3));
            }
#pragma unroll
            for (int mt = 0; mt < 2; mt++)
#pragma unroll
                for (int nt = 0; nt < 4; nt++)
                    acc[mt][nt] = __builtin_amdgcn_mfma_f32_16x16x32_bf16(
                        af[mt], bf[nt], acc[mt][nt], 0, 0, 0);
        }
        cur ^= 1;
    }

#pragma unroll
    for (int mt = 0; mt < 2; mt++)
#pragma unroll
        for (int nt = 0; nt < 4; nt++)
#pragma unroll
            for (int r = 0; r < 4; r++) {
                int row = m0 + wm + mt * 16 + quad * 4 + r;
                int col = n0 + nt * 16 + l16;
                C[(size_t)row * D_ + col] = acc[mt][nt][r];
            }
}

// ---------------------------------------------------------------------------
// Flash attention (causal), 32x32x16 MFMA, in-register softmax (cvt_pk +
// permlane32_swap), triple-buffered K/V with counted vmcnt(4) + raw s_barrier.
// Block = 4 waves x 32 q-rows = 128 q-rows.
// Decomposition (all blocks exactly 17 key-tiles):
//   u<8 : seg0 = q-tile u COMPLETE  (tiles 0..2u+1)      -> direct Y (scaled)
//         seg1 = q-tile 15-u tiles 17..31-2u             -> partial buf0
//   u>=8: q-tile u tiles 0..16                           -> partial buf1
// Grid (16,16,2)=512 blocks = 2/CU; LDS 80KB.
// ---------------------------------------------------------------------------
__global__ __launch_bounds__(256, 2) void flash(const u16* __restrict__ QKV,
                                                const u16* __restrict__ Vtr,
                                                u16* __restrict__ Y,
                                                float* __restrict__ Opart,
                                                float* __restrict__ Lpart) {
    const int u  = blockIdx.x;
    const int h  = blockIdx.y;
    const int b  = blockIdx.z;
    const int g  = h >> 2;
    const int w    = threadIdx.x >> 6;
    const int lane = threadIdx.x & 63;
    const int ln31 = lane & 31;
    const int hi   = lane >> 5;
    const int swz  = lane & 7;

    __shared__ u16 Kb[3][4096];
    __shared__ u16 Vb[3][4096];
    __shared__ float Ot[4][2048];

    const int srow = w * 16 + (lane >> 3);
    const int sseg = (lane & 7) ^ ((lane >> 3) & 7);
    const u16* kgb = QKV + (size_t)(b * T_ + srow) * QS_ + D_ + g * 64 + sseg * 8;
    const u16* vgb = Vtr + (size_t)((b * 4 + g) * 64 + srow) * T_ + sseg * 8;

    auto stage = [&](int tile, int bi) {
        const u16* kg = kgb + (size_t)tile * 64 * QS_;
        const u16* vg = vgb + (size_t)tile * 64;
        u16* kl = &Kb[bi][w * 1024 + lane * 8];
        u16* vl = &Vb[bi][w * 1024 + lane * 8];
        async16(kg, kl);
        async16(kg + (size_t)8 * QS_, kl + 512);
        async16(vg, vl);
        async16(vg + (size_t)8 * T_, vl + 512);
    };
    const bool low = (u < 8);
    auto tileOf = [&](int gidx) {
        return (low && gidx > 2 * u + 1) ? gidx + 15 - 2 * u : gidx;
    };

    stage(tileOf(0), 0);
    stage(tileOf(1), 1);

    const int nseg = low ? 2 : 1;
    const int buf  = low ? 0 : 1;
    int gi = 0;
    for (int seg = 0; seg < nseg; ++seg) {
        const int jt   = (low && seg == 0) ? u : (low ? 15 - u : u);
        const int nIt  = (low && seg == 0) ? 2 * u + 2 : (low ? 15 - 2 * u : 17);
        const bool direct = low && (seg == 0);
        const int qrow = jt * 128 + w * 32 + ln31;

        const u16* qp = QKV + (size_t)(b * T_ + qrow) * QS_ + h * HD_;
        short8 aq[4];
#pragma unroll
        for (int kc = 0; kc < 4; kc++)
            aq[kc] = *(const short8*)(qp + kc * 16 + hi * 8);

        floatx16 acc[2];
#pragma unroll
        for (int dh = 0; dh < 2; dh++)
#pragma unroll
            for (int i = 0; i < 16; i++) acc[dh][i] = 0.f;
        float l = 0.f;

        for (int itn = 0; itn < nIt; ++itn, ++gi) {
            const int tk = tileOf(gi);
            // counted vmcnt: own tile-gi loads done; next tile stays in flight
            if (gi == 16) asm volatile("s_waitcnt vmcnt(0)" ::: "memory");
            else          asm volatile("s_waitcnt vmcnt(4)" ::: "memory");
            __builtin_amdgcn_s_barrier();
            asm volatile("" ::: "memory");

            const int bc = gi % 3;
            if (gi + 2 <= 16) stage(tileOf(gi + 2), (gi + 2) % 3);

            const u16* Kp = &Kb[bc][0];
            const u16* Vp = &Vb[bc][0];
            short8 kf[2][4], vfr[2][4];
#pragma unroll
            for (int kh = 0; kh < 2; kh++)
#pragma unroll
                for (int kc = 0; kc < 4; kc++)
                    kf[kh][kc] = *(const short8*)(Kp + (kh * 32 + ln31) * 64 +
                                                  (((kc * 2 + hi) ^ swz) << 3));
#pragma unroll
            for (int dh = 0; dh < 2; dh++)
#pragma unroll
                for (int kc = 0; kc < 4; kc++)
                    vfr[dh][kc] = *(const short8*)(Vp + (dh * 32 + ln31) * 64 +
                                                   (((kc * 2 + hi) ^ swz) << 3));

            floatx16 s[2];
#pragma unroll
            for (int kh = 0; kh < 2; kh++)
#pragma unroll
                for (int i = 0; i < 16; i++) s[kh][i] = 0.f;

            __builtin_amdgcn_s_setprio(1);
#pragma unroll
            for (int kc = 0; kc < 4; kc++) {
                s[0] = __builtin_amdgcn_mfma_f32_32x32x16_bf16(kf[0][kc], aq[kc], s[0], 0, 0, 0);
                s[1] = __builtin_amdgcn_mfma_f32_32x32x16_bf16(kf[1][kc], aq[kc], s[1], 0, 0, 0);
            }
            __builtin_amdgcn_s_setprio(0);

            // softmax: exp2 + optional causal mask, pack to bf16 pairs inline
            u32 pw[2][8];
            if (tk >= 2 * jt) {
#pragma unroll
                for (int kh = 0; kh < 2; kh++)
#pragma unroll
                    for (int i = 0; i < 8; i++) {
                        int key0 = tk * 64 + kh * 32 +
                                   ((2 * i) & 3) + (((2 * i) >> 2) << 3) + (hi << 2);
                        float e0 = __builtin_amdgcn_exp2f(s[kh][2 * i]);
                        float e1 = __builtin_amdgcn_exp2f(s[kh][2 * i + 1]);
                        e0 = (key0 <= qrow) ? e0 : 0.f;
                        e1 = (key0 + 1 <= qrow) ? e1 : 0.f;
                        l += e0 + e1;
                        pw[kh][i] = cvtpk(e0, e1);
                    }
            } else {
#pragma unroll
                for (int kh = 0; kh < 2; kh++)
#pragma unroll
                    for (int i = 0; i < 8; i++) {
                        float e0 = __builtin_amdgcn_exp2f(s[kh][2 * i]);
                        float e1 = __builtin_amdgcn_exp2f(s[kh][2 * i + 1]);
                        l += e0 + e1;
                        pw[kh][i] = cvtpk(e0, e1);
                    }
            }

            // in-register P -> bf16 B-fragments (keys become k-dim)
            short8 pb[4];
#pragma unroll
            for (int kh = 0; kh < 2; kh++) {
                u32 a0 = pw[kh][0], b0 = pw[kh][2], c0 = pw[kh][1], d0 = pw[kh][3];
                swap32(a0, b0); swap32(c0, d0);
                pb[kh * 2] = pkfrag(a0, c0, b0, d0);
                u32 a1 = pw[kh][4], b1 = pw[kh][6], c1 = pw[kh][5], d1 = pw[kh][7];
                swap32(a1, b1); swap32(c1, d1);
                pb[kh * 2 + 1] = pkfrag(a1, c1, b1, d1);
            }

            __builtin_amdgcn_s_setprio(1);
#pragma unroll
            for (int kc = 0; kc < 4; kc++) {
                acc[0] = __builtin_amdgcn_mfma_f32_32x32x16_bf16(vfr[0][kc], pb[kc], acc[0], 0, 0, 0);
                acc[1] = __builtin_amdgcn_mfma_f32_32x32x16_bf16(vfr[1][kc], pb[kc], acc[1], 0, 0, 0);
            }
            __builtin_amdgcn_s_setprio(0);
        }

        // ---- segment epilogue ----
        float la = l, lb = l;
        swap32f(la, lb);                 // combine hi/lo key-half partial sums
        float lt = la + lb;

        if (direct) {
            float inv = 1.0f / lt;       // l is lane-local (q = ln31): scale now
#pragma unroll
            for (int dh = 0; dh < 2; dh++)
#pragma unroll
                for (int i = 0; i < 16; i++) acc[dh][i] *= inv;
        }

        float* ot = &Ot[w][0];           // [32 q][64 d] f32, 16B-seg XOR swizzle
#pragma unroll
        for (int dh = 0; dh < 2; dh++)
#pragma unroll
            for (int g4 = 0; g4 < 4; g4++) {
                int ss = (dh * 8 + g4 * 2 + hi) ^ (ln31 & 7);
                float4 v = make_float4(acc[dh][g4 * 4 + 0], acc[dh][g4 * 4 + 1],
                                       acc[dh][g4 * 4 + 2], acc[dh][g4 * 4 + 3]);
                *(float4*)(ot + ln31 * 64 + ss * 4) = v;
            }
        asm volatile("s_waitcnt lgkmcnt(0)" ::: "memory");

        const int hq = lane >> 4;
        const int s4 = lane & 15;
        if (direct) {
            u16* ybase = Y + (size_t)(b * T_ + jt * 128 + w * 32) * D_ + h * HD_;
#pragma unroll
            for (int it = 0; it < 8; it++) {
                int q2 = it * 4 + hq;
                int ss = s4 ^ (q2 & 7);
                float4 v = *(const float4*)(ot + q2 * 64 + ss * 4);
                uint2 yw;
                yw.x = cvtpk(v.x, v.y);
                yw.y = cvtpk(v.z, v.w);
                *(uint2*)(ybase + (size_t)q2 * D_ + s4 * 4) = yw;
            }
        } else {
            const int rp = jt * 128 + w * 32 - 1024;   // row base within [0,1024)
            float* obase = Opart + ((size_t)((buf * 2 + b) * 1024 + rp)) * 1024
                         + h * HD_;
#pragma unroll
            for (int it = 0; it < 8; it++) {
                int q2 = it * 4 + hq;
                int ss = s4 ^ (q2 & 7);
                float4 v = *(const float4*)(ot + q2 * 64 + ss * 4);
                *(float4*)(obase + (size_t)q2 * 1024 + s4 * 4) = v;
            }
            if (hi == 0)
                Lpart[((size_t)((buf * 2 + b) * 1024 + rp + ln31)) * 16 + h] = lt;
        }
    }
}

// ---------------------------------------------------------------------------
// combine: Y[rows 1024..2047 per b] = (O0+O1) / (l0+l1)
// ---------------------------------------------------------------------------
__global__ __launch_bounds__(256) void combine(const float* __restrict__ Opart,
                                               const float* __restrict__ Lpart,
                                               u16* __restrict__ Y) {
    int e = (blockIdx.x * 256 + threadIdx.x) * 4;   // < 2*1024*1024
    int b = e >> 20;
    int rem = e & 1048575;
    int row = rem >> 10, col = rem & 1023;
    int li = (b * 1024 + row) * 16 + (col >> 6);
    float l0 = Lpart[li];
    float l1 = Lpart[li + 2 * 1024 * 16];
    float inv = 1.0f / (l0 + l1);
    size_t oi = ((size_t)(b * 1024 + row)) * 1024 + col;
    float4 o0 = *(const float4*)(Opart + oi);
    float4 o1 = *(const float4*)(Opart + oi + (size_t)2 * 1024 * 1024);
    short4v y;
    y.x = (short)f2b((o0.x + o1.x) * inv); y.y = (short)f2b((o0.y + o1.y) * inv);
    y.z = (short)f2b((o0.z + o1.z) * inv); y.w = (short)f2b((o0.w + o1.w) * inv);
    *(short4v*)(Y + (size_t)(b * T_ + 1024 + row) * D_ + col) = y;
}

// ---------------------------------------------------------------------------
extern "C" void kernel_launch(void* const* d_in, const int* in_sizes, int n_in,
                              void* d_out, int out_size, void* d_ws, size_t ws_size,
                              hipStream_t stream) {
    const float* x    = (const float*)d_in[0];
    const float* Wq   = (const float*)d_in[1];
    const float* Wk   = (const float*)d_in[2];
    const float* Wv   = (const float*)d_in[3];
    const float* Wp   = (const float*)d_in[4];
    const float* gain = (const float*)d_in[5];
    float* out = (float*)d_out;

    u16* xb   = (u16*)d_ws;
    u16* Wcat = xb + (size_t)NX;
    u16* Wpb  = Wcat + (size_t)(NWQ + NWK + NWV);
    u16* QKV  = Wpb + (size_t)NWP;
    u16* Vt   = QKV + (size_t)M_ * QS_;
    u16* Y    = Vt + (size_t)M_ * KV_;
    float2* tab = (float2*)(Y + (size_t)M_ * D_);          // 65536 float2
    float* Opart = (float*)(tab + 65536);                  // 2buf*2b*1024*1024 f32
    float* Lpart = Opart + (size_t)4 * 1024 * 1024;        // 2buf*2b*1024*16 f32

    prep<<<CAST_BLOCKS + TAB_BLOCKS, 256, 0, stream>>>(x, Wq, Wk, Wv, Wp, xb, tab);

    gemm_qkv<<<dim3(QS_ / 64, M_ / 128), 256, 0, stream>>>(xb, Wcat, QKV, Vt,
                                                           gain, tab);

    flash<<<dim3(16, H_, B_), 256, 0, stream>>>(QKV, Vt, Y, Opart, Lpart);

    combine<<<2048, 256, 0, stream>>>(Opart, Lpart, Y);

    gemm_proj<<<dim3(D_ / 64, M_ / 128), 256, 0, stream>>>(Y, Wpb, out);
}